// Round 4
// baseline (3710.136 us; speedup 1.0000x reference)
//
#include <hip/hip_runtime.h>
#include <math.h>

#define EPS_ 1e-10f
#define MARGIN 2e-3f

__device__ __forceinline__ bool betterf(float v, int i, float w, int j) {
    return (v > w) || (v == w && i < j);
}
__device__ __forceinline__ bool betterd(double v, int i, double w, int j) {
    return (v > w) || (v == w && i < j);
}

// ---------------------------------------------------------------------------
// Fused router: lane = expert. Wave = 8 rows x 64 experts, full K.
// Block = 256 thr (4 waves) = 32 rows. Grid = N/32 = 512 blocks (2/CU).
// x staged in LDS (double-buffered, coalesced); read back as uniform-address
// ds_read_b128 broadcasts. W read as coalesced 256B dword loads (L1/L2-hot).
// Epilogue (top-2 / softmax / rz / near-tie flag) fused in-wave.
// ---------------------------------------------------------------------------
template<int KW>
__global__ __launch_bounds__(256, 2)
void router_fused(const float* __restrict__ x, const float* __restrict__ W,
                  const float* __restrict__ b, int dim, int N,
                  float* __restrict__ ts, int* __restrict__ sel,
                  float* __restrict__ rzrow,
                  int* __restrict__ nflags, int* __restrict__ flaglist)
{
    __shared__ float xs[2][32][KW];

    const int tid  = threadIdx.x;
    const int lane = tid & 63;
    const int wv   = tid >> 6;           // 0..3
    const int row0 = blockIdx.x * 32;

    // staging lanes: thread covers 16B of rows srow and srow+16
    const int srow = tid >> 4;           // 0..15
    const int sk   = (tid & 15) * 4;     // 0..60

    const int nwin = dim / KW;
    float acc[8] = {};

    const float* xsrc0 = x + (size_t)(row0 + srow) * dim + sk;
    const float* xsrc1 = xsrc0 + (size_t)16 * dim;
    const float* wbase = W + lane;

    float4 xa = *(const float4*)xsrc0;
    float4 xb = *(const float4*)xsrc1;
    *(float4*)&xs[0][srow][sk]      = xa;
    *(float4*)&xs[0][srow + 16][sk] = xb;
    __syncthreads();

    for (int w = 0; w < nwin; ++w) {
        const int cur = w & 1;
        if (w + 1 < nwin) {
            xa = *(const float4*)(xsrc0 + (size_t)(w + 1) * KW);
            xb = *(const float4*)(xsrc1 + (size_t)(w + 1) * KW);
        }
        const int kw = w * KW;
#pragma unroll
        for (int k4 = 0; k4 < KW / 4; ++k4) {
            const float w0 = wbase[(size_t)(kw + k4 * 4 + 0) * 64];
            const float w1 = wbase[(size_t)(kw + k4 * 4 + 1) * 64];
            const float w2 = wbase[(size_t)(kw + k4 * 4 + 2) * 64];
            const float w3 = wbase[(size_t)(kw + k4 * 4 + 3) * 64];
#pragma unroll
            for (int r = 0; r < 8; ++r) {
                const float4 xv = *(const float4*)&xs[cur][wv * 8 + r][k4 * 4];
                acc[r] = fmaf(xv.x, w0, acc[r]);
                acc[r] = fmaf(xv.y, w1, acc[r]);
                acc[r] = fmaf(xv.z, w2, acc[r]);
                acc[r] = fmaf(xv.w, w3, acc[r]);
            }
        }
        __syncthreads();
        if (w + 1 < nwin) {
            *(float4*)&xs[cur ^ 1][srow][sk]      = xa;
            *(float4*)&xs[cur ^ 1][srow + 16][sk] = xb;
            __syncthreads();
        }
    }

    // fused epilogue: per-row top-2 / softmax / rz / flag (lane = expert)
    const float bl = b[lane];
#pragma unroll
    for (int r = 0; r < 8; ++r) {
        const int row = row0 + wv * 8 + r;
        const float z = acc[r] + bl;

        float v1 = z, v2 = -3.4e38f;
        int i1 = lane, i2 = 1 << 30;
#pragma unroll
        for (int m = 1; m < 64; m <<= 1) {
            const float w1 = __shfl_xor(v1, m, 64); const int j1 = __shfl_xor(i1, m, 64);
            const float w2 = __shfl_xor(v2, m, 64); const int j2 = __shfl_xor(i2, m, 64);
            if (betterf(w1, j1, v1, i1)) {
                float nv2; int ni2;
                if (betterf(v1, i1, w2, j2)) { nv2 = v1; ni2 = i1; }
                else                         { nv2 = w2; ni2 = j2; }
                v1 = w1; i1 = j1; v2 = nv2; i2 = ni2;
            } else if (betterf(w1, j1, v2, i2)) { v2 = w1; i2 = j1; }
        }

        float m3 = (lane == i1 || lane == i2) ? -3.4e38f : z;
#pragma unroll
        for (int m = 1; m < 64; m <<= 1) m3 = fmaxf(m3, __shfl_xor(m3, m, 64));

        const float ex = expf(z - v1);
        float ssum = ex;
#pragma unroll
        for (int m = 1; m < 64; m <<= 1) ssum += __shfl_xor(ssum, m, 64);
        const float inv = 1.0f / ssum;

        float sc = fminf(fmaxf(ex * inv, EPS_), 1.0f - EPS_);
        float srz = sc / (1.0f - sc);
#pragma unroll
        for (int m = 1; m < 64; m <<= 1) srz += __shfl_xor(srz, m, 64);

        if (lane == 0) {
            const float s1 = fminf(fmaxf(inv, EPS_), 1.0f - EPS_);
            const float s2 = fminf(fmaxf(expf(v2 - v1) * inv, EPS_), 1.0f - EPS_);
            ts[row * 2 + 0] = s1;
            ts[row * 2 + 1] = s2;
            sel[row * 2 + 0] = i1;
            sel[row * 2 + 1] = i2;
            rzrow[row] = srz;
            if ((v1 - v2) < MARGIN || (v2 - m3) < MARGIN) {
                const int slot = atomicAdd(nflags, 1);
                flaglist[slot] = row;
            }
        }
    }
}

// ---------------------------------------------------------------------------
// fp64 recompute of flagged near-tie rows (4 independent accumulator chains).
// ---------------------------------------------------------------------------
__global__ __launch_bounds__(256)
void fixup(const float* __restrict__ x, const float* __restrict__ W,
           const float* __restrict__ b, int dim,
           const int* __restrict__ nflags, const int* __restrict__ flaglist,
           float* __restrict__ ts, int* __restrict__ sel)
{
    __shared__ double red[256];
    const int tid = threadIdx.x;
    const int e = tid & 63;
    const int q = tid >> 6;
    const int nf = *nflags;
    const int quarter = dim >> 2;

    for (int f = blockIdx.x; f < nf; f += gridDim.x) {
        const int row = flaglist[f];
        const float* xr = x + (size_t)row * dim;
        const int k0 = q * quarter;
        double a0 = 0.0, a1 = 0.0, a2 = 0.0, a3 = 0.0;
        for (int k = k0; k < k0 + quarter; k += 4) {
            a0 = fma((double)xr[k + 0], (double)W[(size_t)(k + 0) * 64 + e], a0);
            a1 = fma((double)xr[k + 1], (double)W[(size_t)(k + 1) * 64 + e], a1);
            a2 = fma((double)xr[k + 2], (double)W[(size_t)(k + 2) * 64 + e], a2);
            a3 = fma((double)xr[k + 3], (double)W[(size_t)(k + 3) * 64 + e], a3);
        }
        red[tid] = (a0 + a1) + (a2 + a3);
        __syncthreads();
        if (tid < 128) red[tid] += red[tid + 128];
        __syncthreads();
        if (tid < 64) {
            const double z = red[tid] + red[tid + 64] + (double)b[e];
            double v1 = z, v2 = -1e300;
            int i1 = e, i2 = 1 << 30;
#pragma unroll
            for (int m = 1; m < 64; m <<= 1) {
                const double w1 = __shfl_xor(v1, m, 64); const int j1 = __shfl_xor(i1, m, 64);
                const double w2 = __shfl_xor(v2, m, 64); const int j2 = __shfl_xor(i2, m, 64);
                if (betterd(w1, j1, v1, i1)) {
                    double nv2; int ni2;
                    if (betterd(v1, i1, w2, j2)) { nv2 = v1; ni2 = i1; }
                    else                         { nv2 = w2; ni2 = j2; }
                    v1 = w1; i1 = j1; v2 = nv2; i2 = ni2;
                } else if (betterd(w1, j1, v2, i2)) { v2 = w1; i2 = j1; }
            }
            float sl = expf((float)(z - v1));
            float ssum = sl;
#pragma unroll
            for (int m = 1; m < 64; m <<= 1) ssum += __shfl_xor(ssum, m, 64);
            const float inv = 1.0f / ssum;
            if (e == 0) {
                const float s1 = fminf(fmaxf(inv, EPS_), 1.0f - EPS_);
                const float s2 = fminf(fmaxf(expf((float)(v2 - v1)) * inv, EPS_), 1.0f - EPS_);
                ts[row * 2 + 0] = s1;
                ts[row * 2 + 1] = s2;
                sel[row * 2 + 0] = i1;
                sel[row * 2 + 1] = i2;
            }
        }
        __syncthreads();
    }
}

// per-64-slot-chunk expert counts (transposed layout) + global histogram
__global__ void hist_chunks(const int* __restrict__ sel, int nchunks,
                            int* __restrict__ hist, int* __restrict__ cnt2)
{
    __shared__ int cnt[64];
    const int lane = threadIdx.x;   // 64
    const int c = blockIdx.x;
    cnt[lane] = 0;
    __syncthreads();
    const int ex = sel[c * 64 + lane];
    atomicAdd(&cnt[ex], 1);
    __syncthreads();
    cnt2[(size_t)lane * nchunks + c] = cnt[lane];   // [e][c] for coalesced scan
    if (cnt[lane]) atomicAdd(&hist[lane], cnt[lane]);
}

// per-batch rz sums (deterministic tree)
__global__ void rz_batch(const float* __restrict__ rzrow,
                         const int* __restrict__ bs_p, const int* __restrict__ sl_p,
                         double* __restrict__ bsum)
{
    __shared__ double red[256];
    const int nb = bs_p[0];
    const int seq = sl_p[0];
    for (int bb = blockIdx.x; bb < nb; bb += gridDim.x) {
        double s = 0.0;
        for (int i = threadIdx.x; i < seq; i += 256)
            s += (double)rzrow[(size_t)bb * seq + i];
        red[threadIdx.x] = s;
        __syncthreads();
        for (int st = 128; st > 0; st >>= 1) {
            if (threadIdx.x < st) red[threadIdx.x] += red[threadIdx.x + st];
            __syncthreads();
        }
        if (threadIdx.x == 0) bsum[bb] = red[0];
        __syncthreads();
    }
}

// expert starts (exclusive scan of hist) + out_cnt + rz finalize
__global__ void combine(const int* __restrict__ hist,
                        int* __restrict__ estart,
                        const double* __restrict__ bsum,
                        const int* __restrict__ bs_p,
                        float* __restrict__ out_cnt, float* __restrict__ out_rz)
{
    const int e = threadIdx.x;   // 64
    const int c0 = hist[e];
    int incl = c0;
#pragma unroll
    for (int m = 1; m < 64; m <<= 1) {
        const int w = __shfl_up(incl, m, 64);
        if (e >= m) incl += w;
    }
    estart[e] = incl - c0;
    out_cnt[e] = (float)c0;
    if (e == 0) {
        const int nb = bs_p[0];
        double a = 0.0;
        for (int i = 0; i < nb; ++i) a += log(bsum[i]);
        out_rz[0] = (float)(a / nb);
    }
}

// parallel per-expert scan over chunks: cbase[c][e] = estart[e] + sum_{c'<c} cnt2[e][c']
__global__ __launch_bounds__(1024)
void chunk_scan(const int* __restrict__ cnt2, const int* __restrict__ estart,
                int nchunks, int* __restrict__ cbase)
{
    __shared__ int sc[1024];
    const int e = blockIdx.x;    // 64 blocks
    const int t = threadIdx.x;   // 1024
    const int v = (t < nchunks) ? cnt2[(size_t)e * nchunks + t] : 0;
    sc[t] = v;
    __syncthreads();
#pragma unroll
    for (int off = 1; off < 1024; off <<= 1) {
        const int add = (t >= off) ? sc[t - off] : 0;
        __syncthreads();
        sc[t] += add;
        __syncthreads();
    }
    if (t < nchunks)
        cbase[(size_t)t * 64 + e] = estart[e] + sc[t] - v;   // exclusive
}

// stable scatter per 64-slot chunk
__global__ void scatter(const int* __restrict__ sel, const float* __restrict__ ts,
                        const int* __restrict__ cbase,
                        float* __restrict__ out_sc, float* __restrict__ out_idx)
{
    __shared__ int shx[64];
    const int lane = threadIdx.x;   // 64
    const int c = blockIdx.x;
    const int idx = c * 64 + lane;
    const int ex = sel[idx];
    shx[lane] = ex;
    __syncthreads();
    int pre = 0;
#pragma unroll
    for (int j = 0; j < 64; ++j) pre += (int)((j < lane) && (shx[j] == ex));
    const int pos = cbase[c * 64 + ex] + pre;
    out_sc[pos]  = ts[idx];
    out_idx[pos] = (float)(idx >> 1);
}

extern "C" void kernel_launch(void* const* d_in, const int* in_sizes, int n_in,
                              void* d_out, int out_size, void* d_ws, size_t ws_size,
                              hipStream_t stream)
{
    const float* x = (const float*)d_in[0];
    const float* W = (const float*)d_in[1];
    const float* b = (const float*)d_in[2];
    const int* bs_p = (const int*)d_in[3];
    const int* sl_p = (const int*)d_in[4];

    const int E   = in_sizes[2];           // 64
    const int dim = in_sizes[1] / E;       // 2048
    const int N   = in_sizes[0] / dim;     // 16384
    const int total = N * 2;               // slots
    const int nchunks = total / 64;        // 512

    char* ws = (char*)d_ws;
    size_t off = 0;
    int*    hist     = (int*)(ws + off); off += 256;
    double* bsum     = (double*)(ws + off); off += 512;
    int*    nflags   = (int*)(ws + off); off += 256;
    int*    estart   = (int*)(ws + off); off += 256;
    float*  ts       = (float*)(ws + off); off += (size_t)total * 4;
    int*    sel      = (int*)(ws + off); off += (size_t)total * 4;
    int*    flaglist = (int*)(ws + off); off += (size_t)N * 4;
    float*  rzrow    = (float*)(ws + off); off += (size_t)N * 4;
    int*    cnt2     = (int*)(ws + off); off += (size_t)nchunks * 64 * 4;
    int*    cbase    = (int*)(ws + off); off += (size_t)nchunks * 64 * 4;

    float* out_sc  = (float*)d_out;
    float* out_idx = out_sc + total;
    float* out_cnt = out_idx + total;
    float* out_rz  = out_cnt + E;

    hipMemsetAsync(ws, 0, 1024, stream);

    hipLaunchKernelGGL((router_fused<64>), dim3(N / 32), dim3(256), 0, stream,
                       x, W, b, dim, N, ts, sel, rzrow, nflags, flaglist);
    hipLaunchKernelGGL(fixup, dim3(512), dim3(256), 0, stream,
                       x, W, b, dim, nflags, flaglist, ts, sel);
    hipLaunchKernelGGL(hist_chunks, dim3(nchunks), dim3(64), 0, stream,
                       sel, nchunks, hist, cnt2);
    hipLaunchKernelGGL(rz_batch, dim3(64), dim3(256), 0, stream,
                       rzrow, bs_p, sl_p, bsum);
    hipLaunchKernelGGL(combine, dim3(1), dim3(64), 0, stream,
                       hist, estart, bsum, bs_p, out_cnt, out_rz);
    hipLaunchKernelGGL(chunk_scan, dim3(64), dim3(1024), 0, stream,
                       cnt2, estart, nchunks, cbase);
    hipLaunchKernelGGL(scatter, dim3(nchunks), dim3(64), 0, stream,
                       sel, ts, cbase, out_sc, out_idx);
}

// Round 5
// 246.917 us; speedup vs baseline: 15.0258x; 15.0258x over previous
//
#include <hip/hip_runtime.h>
#include <math.h>

#define EPS_ 1e-10f
#define MARGIN 2e-3f

__device__ __forceinline__ bool betterd(double v, int i, double w, int j) {
    return (v > w) || (v == w && i < j);
}

// ---------------------------------------------------------------------------
// GEMM, lane = row, acc[64] = all experts in registers.
// Block = 64 threads (1 wave) = 64 rows, one K-slice.
// Grid = ks_count * (N/64). zpart[ks][e][row] (lane-coalesced stores).
// x staged through LDS transposed (conflict-free b32 reads);
// W read as wave-uniform float4 loads (1 line each, L1/L2-hot).
// ---------------------------------------------------------------------------
template<int KW>
__global__ __launch_bounds__(64, 2)
void gemm_rows(const float* __restrict__ x, const float* __restrict__ W,
               int dim, int N, int ks_count, int rgs,
               float* __restrict__ zpart)
{
    __shared__ float xT[KW][65];   // [k][row], pad 65 -> bank (k+row)%32

    const int lane = threadIdx.x;
    const int ks = blockIdx.x / rgs;     // consecutive blocks share ks (L1 reuse)
    const int rg = blockIdx.x % rgs;
    const int r0 = rg * 64;
    const int kslice = dim / ks_count;
    const int k0 = ks * kslice;

    float acc[64];
#pragma unroll
    for (int e = 0; e < 64; ++e) acc[e] = 0.0f;

    const int trow = lane >> 3;          // 0..7
    const int tk4  = (lane & 7) * 4;     // 0..28

    for (int w = 0; w < kslice; w += KW) {
        // stage x[64][KW] transposed into LDS
#pragma unroll
        for (int p = 0; p < 8; ++p) {
            const float4 v = *(const float4*)(
                x + (size_t)(r0 + p * 8 + trow) * dim + (k0 + w + tk4));
            xT[tk4 + 0][p * 8 + trow] = v.x;
            xT[tk4 + 1][p * 8 + trow] = v.y;
            xT[tk4 + 2][p * 8 + trow] = v.z;
            xT[tk4 + 3][p * 8 + trow] = v.w;
        }
        __syncthreads();

        const float* wp = W + (size_t)(k0 + w) * 64;
#pragma unroll 1
        for (int k = 0; k < KW; ++k) {
            const float xv = xT[k][lane];
            const float4* __restrict__ wq = (const float4*)(wp + (size_t)k * 64);
#pragma unroll
            for (int q = 0; q < 16; ++q) {
                const float4 wv = wq[q];
                acc[q * 4 + 0] = fmaf(xv, wv.x, acc[q * 4 + 0]);
                acc[q * 4 + 1] = fmaf(xv, wv.y, acc[q * 4 + 1]);
                acc[q * 4 + 2] = fmaf(xv, wv.z, acc[q * 4 + 2]);
                acc[q * 4 + 3] = fmaf(xv, wv.w, acc[q * 4 + 3]);
            }
        }
        __syncthreads();
    }

    float* zp = zpart + ((size_t)ks * 64) * N + r0 + lane;
#pragma unroll
    for (int e = 0; e < 64; ++e)
        zp[(size_t)e * N] = acc[e];
}

// ---------------------------------------------------------------------------
// Epilogue: thread = row. Sum K-split partials (fixed order), + bias,
// in-thread top-2 (ascending e, strict > => lowest index on ties),
// 3rd-max gap flag, softmax, rz row value. No cross-lane ops at all.
// ---------------------------------------------------------------------------
__global__ __launch_bounds__(256)
void epilogue(const float* __restrict__ zpart, const float* __restrict__ b,
              int N, int ks_count,
              float* __restrict__ ts, int* __restrict__ sel,
              float* __restrict__ rzrow,
              int* __restrict__ nflags, int* __restrict__ flaglist)
{
    const int row = blockIdx.x * 256 + threadIdx.x;
    if (row >= N) return;

    float acc[64];
#pragma unroll
    for (int e = 0; e < 64; ++e) acc[e] = b[e];
    for (int ks = 0; ks < ks_count; ++ks) {
        const float* zp = zpart + ((size_t)ks * 64) * N + row;
#pragma unroll
        for (int e = 0; e < 64; ++e) acc[e] += zp[(size_t)e * N];
    }

    // in-thread top-2 with jax tie semantics
    float v1 = -3.4e38f, v2 = -3.4e38f;
    int i1 = 0, i2 = 0;
#pragma unroll
    for (int e = 0; e < 64; ++e) {
        const float v = acc[e];
        if (v > v1)      { v2 = v1; i2 = i1; v1 = v; i1 = e; }
        else if (v > v2) { v2 = v;  i2 = e; }
    }
    float m3 = -3.4e38f;
#pragma unroll
    for (int e = 0; e < 64; ++e) {
        const float v = acc[e];
        const bool skip = (e == i1) || (e == i2);
        m3 = skip ? m3 : fmaxf(m3, v);
    }

    // softmax + rz (in-thread)
    float ssum = 0.0f;
#pragma unroll
    for (int e = 0; e < 64; ++e) { acc[e] = expf(acc[e] - v1); ssum += acc[e]; }
    const float inv = 1.0f / ssum;
    float srz = 0.0f;
#pragma unroll
    for (int e = 0; e < 64; ++e) {
        float sc = fminf(fmaxf(acc[e] * inv, EPS_), 1.0f - EPS_);
        srz += sc / (1.0f - sc);
    }

    const float s1 = fminf(fmaxf(inv, EPS_), 1.0f - EPS_);                 // exp(0)/sum
    const float s2 = fminf(fmaxf(expf(v2 - v1) * inv, EPS_), 1.0f - EPS_);
    ts[row * 2 + 0] = s1;
    ts[row * 2 + 1] = s2;
    sel[row * 2 + 0] = i1;
    sel[row * 2 + 1] = i2;
    rzrow[row] = srz;
    if ((v1 - v2) < MARGIN || (v2 - m3) < MARGIN) {
        const int slot = atomicAdd(nflags, 1);
        flaglist[slot] = row;
    }
}

// ---------------------------------------------------------------------------
// fp64 recompute of flagged near-tie rows (4 independent accumulator chains).
// ---------------------------------------------------------------------------
__global__ __launch_bounds__(256)
void fixup(const float* __restrict__ x, const float* __restrict__ W,
           const float* __restrict__ b, int dim,
           const int* __restrict__ nflags, const int* __restrict__ flaglist,
           float* __restrict__ ts, int* __restrict__ sel)
{
    __shared__ double red[256];
    const int tid = threadIdx.x;
    const int e = tid & 63;
    const int q = tid >> 6;
    const int nf = *nflags;
    const int quarter = dim >> 2;

    for (int f = blockIdx.x; f < nf; f += gridDim.x) {
        const int row = flaglist[f];
        const float* xr = x + (size_t)row * dim;
        const int k0 = q * quarter;
        double a0 = 0.0, a1 = 0.0, a2 = 0.0, a3 = 0.0;
        for (int k = k0; k < k0 + quarter; k += 4) {
            a0 = fma((double)xr[k + 0], (double)W[(size_t)(k + 0) * 64 + e], a0);
            a1 = fma((double)xr[k + 1], (double)W[(size_t)(k + 1) * 64 + e], a1);
            a2 = fma((double)xr[k + 2], (double)W[(size_t)(k + 2) * 64 + e], a2);
            a3 = fma((double)xr[k + 3], (double)W[(size_t)(k + 3) * 64 + e], a3);
        }
        red[tid] = (a0 + a1) + (a2 + a3);
        __syncthreads();
        if (tid < 128) red[tid] += red[tid + 128];
        __syncthreads();
        if (tid < 64) {
            const double z = red[tid] + red[tid + 64] + (double)b[e];
            double v1 = z, v2 = -1e300;
            int i1 = e, i2 = 1 << 30;
#pragma unroll
            for (int m = 1; m < 64; m <<= 1) {
                const double w1 = __shfl_xor(v1, m, 64); const int j1 = __shfl_xor(i1, m, 64);
                const double w2 = __shfl_xor(v2, m, 64); const int j2 = __shfl_xor(i2, m, 64);
                if (betterd(w1, j1, v1, i1)) {
                    double nv2; int ni2;
                    if (betterd(v1, i1, w2, j2)) { nv2 = v1; ni2 = i1; }
                    else                         { nv2 = w2; ni2 = j2; }
                    v1 = w1; i1 = j1; v2 = nv2; i2 = ni2;
                } else if (betterd(w1, j1, v2, i2)) { v2 = w1; i2 = j1; }
            }
            float sl = expf((float)(z - v1));
            float ssum = sl;
#pragma unroll
            for (int m = 1; m < 64; m <<= 1) ssum += __shfl_xor(ssum, m, 64);
            const float inv = 1.0f / ssum;
            if (e == 0) {
                const float s1 = fminf(fmaxf(inv, EPS_), 1.0f - EPS_);
                const float s2 = fminf(fmaxf(expf((float)(v2 - v1)) * inv, EPS_), 1.0f - EPS_);
                ts[row * 2 + 0] = s1;
                ts[row * 2 + 1] = s2;
                sel[row * 2 + 0] = i1;
                sel[row * 2 + 1] = i2;
            }
        }
        __syncthreads();
    }
}

// per-64-slot-chunk expert counts (transposed layout) + global histogram
__global__ void hist_chunks(const int* __restrict__ sel, int nchunks,
                            int* __restrict__ hist, int* __restrict__ cnt2)
{
    __shared__ int cnt[64];
    const int lane = threadIdx.x;   // 64
    const int c = blockIdx.x;
    cnt[lane] = 0;
    __syncthreads();
    const int ex = sel[c * 64 + lane];
    atomicAdd(&cnt[ex], 1);
    __syncthreads();
    cnt2[(size_t)lane * nchunks + c] = cnt[lane];   // [e][c] for coalesced scan
    if (cnt[lane]) atomicAdd(&hist[lane], cnt[lane]);
}

// per-batch rz sums (deterministic tree)
__global__ void rz_batch(const float* __restrict__ rzrow,
                         const int* __restrict__ bs_p, const int* __restrict__ sl_p,
                         double* __restrict__ bsum)
{
    __shared__ double red[256];
    const int nb = bs_p[0];
    const int seq = sl_p[0];
    for (int bb = blockIdx.x; bb < nb; bb += gridDim.x) {
        double s = 0.0;
        for (int i = threadIdx.x; i < seq; i += 256)
            s += (double)rzrow[(size_t)bb * seq + i];
        red[threadIdx.x] = s;
        __syncthreads();
        for (int st = 128; st > 0; st >>= 1) {
            if (threadIdx.x < st) red[threadIdx.x] += red[threadIdx.x + st];
            __syncthreads();
        }
        if (threadIdx.x == 0) bsum[bb] = red[0];
        __syncthreads();
    }
}

// expert starts (exclusive scan of hist) + out_cnt + rz finalize
__global__ void combine(const int* __restrict__ hist,
                        int* __restrict__ estart,
                        const double* __restrict__ bsum,
                        const int* __restrict__ bs_p,
                        float* __restrict__ out_cnt, float* __restrict__ out_rz)
{
    const int e = threadIdx.x;   // 64
    const int c0 = hist[e];
    int incl = c0;
#pragma unroll
    for (int m = 1; m < 64; m <<= 1) {
        const int w = __shfl_up(incl, m, 64);
        if (e >= m) incl += w;
    }
    estart[e] = incl - c0;
    out_cnt[e] = (float)c0;
    if (e == 0) {
        const int nb = bs_p[0];
        double a = 0.0;
        for (int i = 0; i < nb; ++i) a += log(bsum[i]);
        out_rz[0] = (float)(a / nb);
    }
}

// parallel per-expert scan over chunks
__global__ __launch_bounds__(1024)
void chunk_scan(const int* __restrict__ cnt2, const int* __restrict__ estart,
                int nchunks, int* __restrict__ cbase)
{
    __shared__ int sc[1024];
    const int e = blockIdx.x;    // 64 blocks
    const int t = threadIdx.x;   // 1024
    const int v = (t < nchunks) ? cnt2[(size_t)e * nchunks + t] : 0;
    sc[t] = v;
    __syncthreads();
#pragma unroll
    for (int off = 1; off < 1024; off <<= 1) {
        const int add = (t >= off) ? sc[t - off] : 0;
        __syncthreads();
        sc[t] += add;
        __syncthreads();
    }
    if (t < nchunks)
        cbase[(size_t)t * 64 + e] = estart[e] + sc[t] - v;   // exclusive
}

// stable scatter per 64-slot chunk
__global__ void scatter(const int* __restrict__ sel, const float* __restrict__ ts,
                        const int* __restrict__ cbase,
                        float* __restrict__ out_sc, float* __restrict__ out_idx)
{
    __shared__ int shx[64];
    const int lane = threadIdx.x;   // 64
    const int c = blockIdx.x;
    const int idx = c * 64 + lane;
    const int ex = sel[idx];
    shx[lane] = ex;
    __syncthreads();
    int pre = 0;
#pragma unroll
    for (int j = 0; j < 64; ++j) pre += (int)((j < lane) && (shx[j] == ex));
    const int pos = cbase[c * 64 + ex] + pre;
    out_sc[pos]  = ts[idx];
    out_idx[pos] = (float)(idx >> 1);
}

extern "C" void kernel_launch(void* const* d_in, const int* in_sizes, int n_in,
                              void* d_out, int out_size, void* d_ws, size_t ws_size,
                              hipStream_t stream)
{
    const float* x = (const float*)d_in[0];
    const float* W = (const float*)d_in[1];
    const float* b = (const float*)d_in[2];
    const int* bs_p = (const int*)d_in[3];
    const int* sl_p = (const int*)d_in[4];

    const int E   = in_sizes[2];           // 64
    const int dim = in_sizes[1] / E;       // 2048
    const int N   = in_sizes[0] / dim;     // 16384
    const int total = N * 2;               // slots
    const int nchunks = total / 64;        // 512

    char* ws = (char*)d_ws;
    size_t off = 0;
    int*    hist     = (int*)(ws + off); off += 256;
    double* bsum     = (double*)(ws + off); off += 512;
    int*    nflags   = (int*)(ws + off); off += 256;
    int*    estart   = (int*)(ws + off); off += 256;
    float*  ts       = (float*)(ws + off); off += (size_t)total * 4;
    int*    sel      = (int*)(ws + off); off += (size_t)total * 4;
    int*    flaglist = (int*)(ws + off); off += (size_t)N * 4;
    float*  rzrow    = (float*)(ws + off); off += (size_t)N * 4;
    int*    cnt2     = (int*)(ws + off); off += (size_t)nchunks * 64 * 4;
    int*    cbase    = (int*)(ws + off); off += (size_t)nchunks * 64 * 4;

    // pick largest ksplit whose zpart fits the workspace
    int ksplit = 8;
    while (ksplit > 1 &&
           off + (size_t)ksplit * N * 64 * sizeof(float) > ws_size)
        ksplit >>= 1;
    float* zpart = (float*)(ws + off);

    float* out_sc  = (float*)d_out;
    float* out_idx = out_sc + total;
    float* out_cnt = out_idx + total;
    float* out_rz  = out_cnt + E;

    hipMemsetAsync(ws, 0, 1280, stream);

    const int rgs = N / 64;  // 256 row groups
    hipLaunchKernelGGL((gemm_rows<32>), dim3(rgs * ksplit), dim3(64), 0, stream,
                       x, W, dim, N, ksplit, rgs, zpart);
    hipLaunchKernelGGL(epilogue, dim3(N / 256), dim3(256), 0, stream,
                       zpart, b, N, ksplit, ts, sel, rzrow, nflags, flaglist);
    hipLaunchKernelGGL(fixup, dim3(512), dim3(256), 0, stream,
                       x, W, b, dim, nflags, flaglist, ts, sel);
    hipLaunchKernelGGL(hist_chunks, dim3(nchunks), dim3(64), 0, stream,
                       sel, nchunks, hist, cnt2);
    hipLaunchKernelGGL(rz_batch, dim3(64), dim3(256), 0, stream,
                       rzrow, bs_p, sl_p, bsum);
    hipLaunchKernelGGL(combine, dim3(1), dim3(64), 0, stream,
                       hist, estart, bsum, bs_p, out_cnt, out_rz);
    hipLaunchKernelGGL(chunk_scan, dim3(64), dim3(1024), 0, stream,
                       cnt2, estart, nchunks, cbase);
    hipLaunchKernelGGL(scatter, dim3(nchunks), dim3(64), 0, stream,
                       sel, ts, cbase, out_sc, out_idx);
}